// Round 1
// baseline (1083.387 us; speedup 1.0000x reference)
//
#include <hip/hip_runtime.h>

typedef unsigned short u16;
typedef __bf16 v8bf __attribute__((ext_vector_type(8)));
typedef unsigned short u16x8 __attribute__((ext_vector_type(8)));
typedef float v4f __attribute__((ext_vector_type(4)));

#define DEV __device__ __forceinline__

constexpr int M_TOK = 512 * 77;   // 39424 = 128*308

DEV u16 f2bf(float f) {
  union { float f; unsigned int u; } v; v.f = f;
  unsigned int r = v.u + 0x7fffu + ((v.u >> 16) & 1u);
  return (u16)(r >> 16);
}

DEV void gload16(const void* g, void* l) {
  __builtin_amdgcn_global_load_lds((const __attribute__((address_space(1))) void*)g,
                                   (__attribute__((address_space(3))) void*)l, 16, 0, 0);
}

// ---------------- fp32 -> bf16 convert (x4 vectorized), optional scale ----------------
__global__ void cvt4_k(const float* __restrict__ src, u16* __restrict__ dst, int n4, float scale) {
  int i = blockIdx.x * blockDim.x + threadIdx.x;
  if (i >= n4) return;
  const float4 v = ((const float4*)src)[i];
  ushort4 o;
  o.x = f2bf(v.x * scale); o.y = f2bf(v.y * scale);
  o.z = f2bf(v.z * scale); o.w = f2bf(v.w * scale);
  ((ushort4*)dst)[i] = o;
}

// concat qkv bias, q part scaled by 0.125
__global__ void qkvb_k(const float* __restrict__ qb, const float* __restrict__ kb,
                       const float* __restrict__ vb, float* __restrict__ dst) {
  int i = blockIdx.x * 256 + threadIdx.x;
  if (i >= 2304) return;
  dst[i] = (i < 768) ? qb[i] * 0.125f : (i < 1536 ? kb[i - 768] : vb[i - 1536]);
}

// ---------------- LayerNorm: one wave per row of 768, writes bf16 ----------------
__global__ __launch_bounds__(256) void ln_k(const float* __restrict__ x, const float* __restrict__ w,
                                            const float* __restrict__ bvec, u16* __restrict__ out, int nrows) {
  const int lane = threadIdx.x & 63;
  const int row = blockIdx.x * 4 + (threadIdx.x >> 6);
  if (row >= nrows) return;
  const float4* xr = (const float4*)(x + (size_t)row * 768);
  float4 v[3];
  float sum = 0.f, sq = 0.f;
#pragma unroll
  for (int t = 0; t < 3; ++t) {
    v[t] = xr[lane + 64 * t];
    sum += v[t].x + v[t].y + v[t].z + v[t].w;
    sq  += v[t].x * v[t].x + v[t].y * v[t].y + v[t].z * v[t].z + v[t].w * v[t].w;
  }
#pragma unroll
  for (int o = 1; o < 64; o <<= 1) { sum += __shfl_xor(sum, o, 64); sq += __shfl_xor(sq, o, 64); }
  const float mean = sum * (1.f / 768.f);
  const float inv = rsqrtf(sq * (1.f / 768.f) - mean * mean + 1e-5f);
  u16* orow = out + (size_t)row * 768;
#pragma unroll
  for (int t = 0; t < 3; ++t) {
    const int c = 4 * (lane + 64 * t);
    ushort4 o4;
    o4.x = f2bf((v[t].x - mean) * inv * w[c + 0] + bvec[c + 0]);
    o4.y = f2bf((v[t].y - mean) * inv * w[c + 1] + bvec[c + 1]);
    o4.z = f2bf((v[t].z - mean) * inv * w[c + 2] + bvec[c + 2]);
    o4.w = f2bf((v[t].w - mean) * inv * w[c + 3] + bvec[c + 3]);
    *(ushort4*)(orow + c) = o4;
  }
}

// ---------------- GEMM: out[M][N] = act(A[M][K](bf16) @ B[N][K]^T(bf16) + bias) [+res] ----------------
// m97 structure: 128x128 tile, BK=32, 4 waves (each 64x64 = 4x4 frags of 16x16x32 MFMA),
// global_load_lds width-16 staging, double LDS buffer, one barrier per K-step.
template <int OUTF32, int ACT, int RES>
__global__ __launch_bounds__(256, 2) void gemm_k(
    const u16* __restrict__ A, const u16* __restrict__ Bw,
    const float* __restrict__ bias, const float* __restrict__ res,
    void* __restrict__ out, int M, int N, int K) {
  __shared__ u16 sA[2][128 * 32];
  __shared__ u16 sB[2][128 * 32];
  const int tid = threadIdx.x;
  const int lane = tid & 63;
  const int wv = tid >> 6;
  const int wr = wv >> 1, wc = wv & 1;
  const int m0 = blockIdx.y * 128, n0 = blockIdx.x * 128;
  const int frow = lane & 15, fk = (lane >> 4) * 8;

  v4f acc[4][4];
#pragma unroll
  for (int i = 0; i < 4; ++i)
#pragma unroll
    for (int j = 0; j < 4; ++j) acc[i][j] = (v4f){0.f, 0.f, 0.f, 0.f};

  // staging addressing: per-thread 16B chunk c: t_lin = c*256+tid; row=t_lin>>2; kcol8=(t_lin&3)*8
  const int srow = tid >> 2;
  const int skc = (tid & 3) * 8;
  const size_t aBase0 = (size_t)(m0 + srow) * K + skc;
  const size_t aBase1 = (size_t)(m0 + 64 + srow) * K + skc;
  const size_t bBase0 = (size_t)(n0 + srow) * K + skc;
  const size_t bBase1 = (size_t)(n0 + 64 + srow) * K + skc;
  const int ldsOff0 = (tid & ~63) * 8;  // wave-uniform; HW adds lane*16B

  auto stage = [&](int buf, int kt) {
    const int kb = kt * 32;
    gload16(A + aBase0 + kb, &sA[buf][ldsOff0]);
    gload16(A + aBase1 + kb, &sA[buf][2048 + ldsOff0]);
    gload16(Bw + bBase0 + kb, &sB[buf][ldsOff0]);
    gload16(Bw + bBase1 + kb, &sB[buf][2048 + ldsOff0]);
  };

  const int KT = K >> 5;
  stage(0, 0);
  __syncthreads();
  for (int kt = 0; kt < KT; ++kt) {
    const int cur = kt & 1;
    if (kt + 1 < KT) stage(cur ^ 1, kt + 1);
    v8bf fa[4], fb[4];
#pragma unroll
    for (int i = 0; i < 4; ++i)
      fa[i] = *(const v8bf*)&sA[cur][(wr * 64 + i * 16 + frow) * 32 + fk];
#pragma unroll
    for (int j = 0; j < 4; ++j)
      fb[j] = *(const v8bf*)&sB[cur][(wc * 64 + j * 16 + frow) * 32 + fk];
#pragma unroll
    for (int i = 0; i < 4; ++i)
#pragma unroll
      for (int j = 0; j < 4; ++j)
        acc[i][j] = __builtin_amdgcn_mfma_f32_16x16x32_bf16(fa[i], fb[j], acc[i][j], 0, 0, 0);
    __syncthreads();
  }

  // epilogue: C/D layout col=lane&15, row=(lane>>4)*4+r
#pragma unroll
  for (int i = 0; i < 4; ++i) {
    const int rowb = m0 + wr * 64 + i * 16 + (lane >> 4) * 4;
#pragma unroll
    for (int j = 0; j < 4; ++j) {
      const int col = n0 + wc * 64 + j * 16 + (lane & 15);
      const float bv = bias[col];
#pragma unroll
      for (int r = 0; r < 4; ++r) {
        float v = acc[i][j][r] + bv;
        if (ACT) v = v * (1.f / (1.f + __expf(-1.702f * v)));  // QuickGELU
        const size_t off = (size_t)(rowb + r) * N + col;
        if (RES) v += res[off];
        if (OUTF32) ((float*)out)[off] = v;
        else ((u16*)out)[off] = f2bf(v);
      }
    }
  }
}

// ---------------- attention: one block per (b,h); S=77 padded to 80 ----------------
__global__ __launch_bounds__(256) void attn_k(const u16* __restrict__ qkv, u16* __restrict__ ctx) {
  __shared__ u16 sQK[10240];        // sQ[80][64] @0, sK[80][64] @5120; later reused as sP[80][96]
  __shared__ u16 sVt[64 * 120];     // V transposed [d][k], stride 120 (bank-spread, 16B-mult)
  __shared__ float sS[80][81];      // scores fp32, stride 81 (conflict-free column walks)
  const int tid = threadIdx.x;
  const int lane = tid & 63;
  const int wv = tid >> 6;
  const int b = blockIdx.x / 12;
  const int h = blockIdx.x % 12;
  u16* sQ = sQK;
  u16* sK = sQK + 5120;
  u16* sP = sQK;

  for (int i = tid; i < 10240 + 64 * 120; i += 256) {
    if (i < 10240) sQK[i] = 0; else sVt[i - 10240] = 0;
  }
  __syncthreads();

  const size_t tokBase = (size_t)(b * 77) * 2304 + h * 64;
  for (int c = tid; c < 77 * 8; c += 256) {
    const int row = c >> 3, k8 = (c & 7) * 8;
    const size_t src = tokBase + (size_t)row * 2304 + k8;
    *(u16x8*)&sQ[row * 64 + k8] = *(const u16x8*)&qkv[src];
    *(u16x8*)&sK[row * 64 + k8] = *(const u16x8*)&qkv[src + 768];
    u16x8 v = *(const u16x8*)&qkv[src + 1536];
#pragma unroll
    for (int j = 0; j < 8; ++j) sVt[(k8 + j) * 120 + row] = v[j];
  }
  __syncthreads();

  const int frow = lane & 15, fk = (lane >> 4) * 8;
  // scores S = Q K^T (q pre-scaled by 0.125 via folded weights), causal mask
  for (int t = wv; t < 25; t += 4) {
    const int it = t / 5, jt = t % 5;
    v4f acc = {0.f, 0.f, 0.f, 0.f};
#pragma unroll
    for (int kk = 0; kk < 2; ++kk) {
      v8bf a = *(const v8bf*)&sQ[(it * 16 + frow) * 64 + kk * 32 + fk];
      v8bf bb = *(const v8bf*)&sK[(jt * 16 + frow) * 64 + kk * 32 + fk];
      acc = __builtin_amdgcn_mfma_f32_16x16x32_bf16(a, bb, acc, 0, 0, 0);
    }
    const int col = jt * 16 + frow;
#pragma unroll
    for (int r = 0; r < 4; ++r) {
      const int row = it * 16 + (lane >> 4) * 4 + r;
      sS[row][col] = (col > row) ? -1e30f : acc[r];
    }
  }
  __syncthreads();

  // row softmax (threads 0..79), write P as bf16 into sP[80][96] (cols 80..95 zero)
  if (tid < 80) {
    const int row = tid;
    float mx = -1e30f;
    for (int c2 = 0; c2 < 80; ++c2) mx = fmaxf(mx, sS[row][c2]);
    float sum = 0.f;
    for (int c2 = 0; c2 < 80; ++c2) { float e = __expf(sS[row][c2] - mx); sum += e; sS[row][c2] = e; }
    const float inv = 1.f / sum;
    for (int c2 = 0; c2 < 80; ++c2) sP[row * 96 + c2] = f2bf(sS[row][c2] * inv);
    for (int c2 = 80; c2 < 96; ++c2) sP[row * 96 + c2] = 0;
  }
  __syncthreads();

  // ctx = P @ V : A=sP[80][96], B[k][d]=V -> read sVt[d][k]
  const size_t outBase = (size_t)(b * 77) * 768 + h * 64;
  for (int t = wv; t < 20; t += 4) {
    const int it = t / 4, jt = t % 4;
    v4f acc = {0.f, 0.f, 0.f, 0.f};
#pragma unroll
    for (int kk = 0; kk < 3; ++kk) {
      v8bf a = *(const v8bf*)&sP[(it * 16 + frow) * 96 + kk * 32 + fk];
      v8bf bb = *(const v8bf*)&sVt[(jt * 16 + frow) * 120 + kk * 32 + fk];
      acc = __builtin_amdgcn_mfma_f32_16x16x32_bf16(a, bb, acc, 0, 0, 0);
    }
    const int col = jt * 16 + frow;
#pragma unroll
    for (int r = 0; r < 4; ++r) {
      const int row = it * 16 + (lane >> 4) * 4 + r;
      if (row < 77) ctx[outBase + (size_t)row * 768 + col] = f2bf(acc[r]);
    }
  }
}

// ---------------- launch ----------------
extern "C" void kernel_launch(void* const* d_in, const int* in_sizes, int n_in,
                              void* d_out, int out_size, void* d_ws, size_t ws_size,
                              hipStream_t stream) {
  const float* x    = (const float*)d_in[0];
  const float* ln1w = (const float*)d_in[1];
  const float* ln1b = (const float*)d_in[2];
  const float* qw   = (const float*)d_in[3];
  const float* qb   = (const float*)d_in[4];
  const float* kw   = (const float*)d_in[5];
  const float* kb   = (const float*)d_in[6];
  const float* vw   = (const float*)d_in[7];
  const float* vb   = (const float*)d_in[8];
  const float* ow   = (const float*)d_in[9];
  const float* ob   = (const float*)d_in[10];
  const float* ln2w = (const float*)d_in[11];
  const float* ln2b = (const float*)d_in[12];
  const float* f1wf = (const float*)d_in[13];
  const float* f1b  = (const float*)d_in[14];
  const float* f2wf = (const float*)d_in[15];
  const float* f2b  = (const float*)d_in[16];
  float* outp = (float*)d_out;

  char* p = (char*)d_ws;
  auto alloc = [&](size_t bytes) { char* r = p; p += (bytes + 255) & ~(size_t)255; return r; };
  u16* wqkv = (u16*)alloc((size_t)2304 * 768 * 2);   // rows: qw*0.125 | kw | vw
  u16* owb  = (u16*)alloc((size_t)768 * 768 * 2);
  u16* f1w  = (u16*)alloc((size_t)3072 * 768 * 2);
  u16* f2w  = (u16*)alloc((size_t)768 * 3072 * 2);
  float* qkvb = (float*)alloc(2304 * 4);
  u16* bufA = (u16*)alloc((size_t)M_TOK * 768 * 2);   // h -> ctx -> h2in
  u16* bufB = (u16*)alloc((size_t)M_TOK * 3072 * 2);  // qkv (2304 cols) -> h2 (3072 cols)

  // weight/bias conversion (x1 = attn residual lives in d_out; q-scale folded here)
  cvt4_k<<<576, 256, 0, stream>>>(qw, wqkv, 147456, 0.125f);
  cvt4_k<<<576, 256, 0, stream>>>(kw, wqkv + 589824, 147456, 1.f);
  cvt4_k<<<576, 256, 0, stream>>>(vw, wqkv + 1179648, 147456, 1.f);
  cvt4_k<<<576, 256, 0, stream>>>(ow, owb, 147456, 1.f);
  cvt4_k<<<2304, 256, 0, stream>>>(f1wf, f1w, 589824, 1.f);
  cvt4_k<<<2304, 256, 0, stream>>>(f2wf, f2w, 589824, 1.f);
  qkvb_k<<<9, 256, 0, stream>>>(qb, kb, vb, qkvb);

  ln_k<<<M_TOK / 4, 256, 0, stream>>>(x, ln1w, ln1b, bufA, M_TOK);
  gemm_k<0, 0, 0><<<dim3(18, 308), 256, 0, stream>>>(bufA, wqkv, qkvb, nullptr, bufB, M_TOK, 2304, 768);
  attn_k<<<512 * 12, 256, 0, stream>>>(bufB, bufA);
  gemm_k<1, 0, 1><<<dim3(6, 308), 256, 0, stream>>>(bufA, owb, ob, x, outp, M_TOK, 768, 768);
  ln_k<<<M_TOK / 4, 256, 0, stream>>>(outp, ln2w, ln2b, bufA, M_TOK);
  gemm_k<0, 1, 0><<<dim3(24, 308), 256, 0, stream>>>(bufA, f1w, f1b, nullptr, bufB, M_TOK, 3072, 768);
  gemm_k<1, 0, 1><<<dim3(6, 308), 256, 0, stream>>>(bufB, f2w, f2b, outp, outp, M_TOK, 768, 3072);
}

// Round 2
// 976.364 us; speedup vs baseline: 1.1096x; 1.1096x over previous
//
#include <hip/hip_runtime.h>

typedef unsigned short u16;
typedef __bf16 v8bf __attribute__((ext_vector_type(8)));
typedef unsigned short u16x8 __attribute__((ext_vector_type(8)));
typedef float v4f __attribute__((ext_vector_type(4)));

#define DEV __device__ __forceinline__

constexpr int M_TOK = 512 * 77;   // 39424 = 256*154

DEV u16 f2bf(float f) {
  union { float f; unsigned int u; } v; v.f = f;
  unsigned int r = v.u + 0x7fffu + ((v.u >> 16) & 1u);
  return (u16)(r >> 16);
}

DEV void gload16(const void* g, void* l) {
  __builtin_amdgcn_global_load_lds((const __attribute__((address_space(1))) void*)g,
                                   (__attribute__((address_space(3))) void*)l, 16, 0, 0);
}

DEV v4f MF(v8bf a, v8bf b, v4f c) {
  return __builtin_amdgcn_mfma_f32_16x16x32_bf16(a, b, c, 0, 0, 0);
}

// ---------------- fp32 -> bf16 convert (x4 vectorized), optional scale ----------------
__global__ void cvt4_k(const float* __restrict__ src, u16* __restrict__ dst, int n4, float scale) {
  int i = blockIdx.x * blockDim.x + threadIdx.x;
  if (i >= n4) return;
  const float4 v = ((const float4*)src)[i];
  ushort4 o;
  o.x = f2bf(v.x * scale); o.y = f2bf(v.y * scale);
  o.z = f2bf(v.z * scale); o.w = f2bf(v.w * scale);
  ((ushort4*)dst)[i] = o;
}

__global__ void qkvb_k(const float* __restrict__ qb, const float* __restrict__ kb,
                       const float* __restrict__ vb, float* __restrict__ dst) {
  int i = blockIdx.x * 256 + threadIdx.x;
  if (i >= 2304) return;
  dst[i] = (i < 768) ? qb[i] * 0.125f : (i < 1536 ? kb[i - 768] : vb[i - 1536]);
}

// ---------------- LayerNorm: one wave per row of 768, writes bf16 ----------------
__global__ __launch_bounds__(256) void ln_k(const float* __restrict__ x, const float* __restrict__ w,
                                            const float* __restrict__ bvec, u16* __restrict__ out, int nrows) {
  const int lane = threadIdx.x & 63;
  const int row = blockIdx.x * 4 + (threadIdx.x >> 6);
  if (row >= nrows) return;
  const float4* xr = (const float4*)(x + (size_t)row * 768);
  float4 v[3];
  float sum = 0.f, sq = 0.f;
#pragma unroll
  for (int t = 0; t < 3; ++t) {
    v[t] = xr[lane + 64 * t];
    sum += v[t].x + v[t].y + v[t].z + v[t].w;
    sq  += v[t].x * v[t].x + v[t].y * v[t].y + v[t].z * v[t].z + v[t].w * v[t].w;
  }
#pragma unroll
  for (int o = 1; o < 64; o <<= 1) { sum += __shfl_xor(sum, o, 64); sq += __shfl_xor(sq, o, 64); }
  const float mean = sum * (1.f / 768.f);
  const float inv = rsqrtf(sq * (1.f / 768.f) - mean * mean + 1e-5f);
  u16* orow = out + (size_t)row * 768;
#pragma unroll
  for (int t = 0; t < 3; ++t) {
    const int c = 4 * (lane + 64 * t);
    ushort4 o4;
    o4.x = f2bf((v[t].x - mean) * inv * w[c + 0] + bvec[c + 0]);
    o4.y = f2bf((v[t].y - mean) * inv * w[c + 1] + bvec[c + 1]);
    o4.z = f2bf((v[t].z - mean) * inv * w[c + 2] + bvec[c + 2]);
    o4.w = f2bf((v[t].w - mean) * inv * w[c + 3] + bvec[c + 3]);
    *(ushort4*)(orow + c) = o4;
  }
}

// ---------------- GEMM 256x256 tile, BK=32, 8 waves, 4-deep LDS ring, counted vmcnt ----
// out[M][N] = act(A[M][K](bf16) @ B[N][K]^T(bf16) + bias) [+res]
// LDS slot = A[256][32] + B[256][32] bf16 (32KB); 4 slots = 128KB.
// XOR chunk-swizzle s(R)=(R&3)^((R>>2)&3) applied on global source + ds_read (both sides).
template <int OUTF32, int ACT, int RES>
__global__ __launch_bounds__(512, 2) void gemm256_k(
    const u16* __restrict__ A, const u16* __restrict__ Bw,
    const float* __restrict__ bias, const float* __restrict__ res,
    void* __restrict__ out, int M, int N, int K, int nbx) {
  __shared__ u16 lds[65536];
  const int tid = threadIdx.x;
  const int lane = tid & 63;
  const int wv = tid >> 6;
  const int wr = wv >> 2, wc = wv & 3;   // wave tile: 128(M) x 64(N)

  // bijective XCD swizzle (m204 form)
  const int nwg = gridDim.x;
  const int q = nwg >> 3, r8 = nwg & 7;
  const int xcd = blockIdx.x & 7, cidx = blockIdx.x >> 3;
  const int wg = (xcd < r8 ? xcd * (q + 1) : r8 * (q + 1) + (xcd - r8) * q) + cidx;
  const int m0 = (wg / nbx) * 256;
  const int n0 = (wg % nbx) * 256;

  const int frow = lane & 15;
  const int fq = lane >> 4;
  const int chunkp = (fq ^ (lane & 3) ^ ((lane >> 2) & 3)) & 3;  // cw ^ s(R), s depends only on frow
  const int aRd = (wr * 128 + frow) * 32 + chunkp * 8;           // u16 index in A region
  const int bRd = (wc * 64 + frow) * 32 + chunkp * 8;            // u16 index in B region

  // staging: thread tid stages 16B of row (g*128 + tid>>2), global chunk pre-swizzled
  const int srow = tid >> 2;
  const int scg = ((tid & 3) ^ (srow & 3) ^ ((srow >> 2) & 3)) & 3;
  const size_t aBase = (size_t)(m0 + srow) * K + scg * 8;
  const size_t bBase = (size_t)(n0 + srow) * K + scg * 8;
  const int ldsW = wv * 512;   // wave-uniform dest; HW adds lane*16B

#define GLDA(kt, g) gload16(A + aBase + (size_t)(g) * 128 * K + (kt) * 32, \
                            &lds[(((kt) & 3) << 14) + ((g) << 12) + ldsW])
#define GLDB(kt, g) gload16(Bw + bBase + (size_t)(g) * 128 * K + (kt) * 32, \
                            &lds[(((kt) & 3) << 14) + 8192 + ((g) << 12) + ldsW])
#define BAR() asm volatile("s_barrier" ::: "memory")

  v4f acc[8][4];
#pragma unroll
  for (int i = 0; i < 8; ++i)
#pragma unroll
    for (int j = 0; j < 4; ++j) acc[i][j] = (v4f){0.f, 0.f, 0.f, 0.f};

  const int NT = K >> 5;   // 24 or 96; NT >= 4, NT % 4 == 0

  // prologue: stage tiles 0,1,2 (12 loads); wait tile 0 (keep 8 in flight)
  GLDA(0, 0); GLDA(0, 1); GLDB(0, 0); GLDB(0, 1);
  GLDA(1, 0); GLDA(1, 1); GLDB(1, 0); GLDB(1, 1);
  GLDA(2, 0); GLDA(2, 1); GLDB(2, 0); GLDB(2, 1);
  asm volatile("s_waitcnt vmcnt(8)" ::: "memory");
  BAR();

  // K-tile body: phase1 = acc rows 0-3 (reads A0-3 + B0-3, stages A of kt+3),
  //              phase2 = acc rows 4-7 (reads A4-7, stages B of kt+3, counted vmcnt)
#define KTILE(kt, STG, VM)                                                      \
  do {                                                                          \
    const int sb = ((kt) & 3) << 14;                                            \
    v8bf fa0 = *(const v8bf*)&lds[sb + aRd +    0];                             \
    v8bf fa1 = *(const v8bf*)&lds[sb + aRd +  512];                             \
    v8bf fa2 = *(const v8bf*)&lds[sb + aRd + 1024];                             \
    v8bf fa3 = *(const v8bf*)&lds[sb + aRd + 1536];                             \
    v8bf fb0 = *(const v8bf*)&lds[sb + 8192 + bRd +    0];                      \
    v8bf fb1 = *(const v8bf*)&lds[sb + 8192 + bRd +  512];                      \
    v8bf fb2 = *(const v8bf*)&lds[sb + 8192 + bRd + 1024];                      \
    v8bf fb3 = *(const v8bf*)&lds[sb + 8192 + bRd + 1536];                      \
    if (STG) { GLDA((kt) + 3, 0); GLDA((kt) + 3, 1); }                          \
    BAR();                                                                      \
    __builtin_amdgcn_s_setprio(1);                                              \
    acc[0][0] = MF(fa0, fb0, acc[0][0]); acc[0][1] = MF(fa0, fb1, acc[0][1]);   \
    acc[0][2] = MF(fa0, fb2, acc[0][2]); acc[0][3] = MF(fa0, fb3, acc[0][3]);   \
    acc[1][0] = MF(fa1, fb0, acc[1][0]); acc[1][1] = MF(fa1, fb1, acc[1][1]);   \
    acc[1][2] = MF(fa1, fb2, acc[1][2]); acc[1][3] = MF(fa1, fb3, acc[1][3]);   \
    acc[2][0] = MF(fa2, fb0, acc[2][0]); acc[2][1] = MF(fa2, fb1, acc[2][1]);   \
    acc[2][2] = MF(fa2, fb2, acc[2][2]); acc[2][3] = MF(fa2, fb3, acc[2][3]);   \
    acc[3][0] = MF(fa3, fb0, acc[3][0]); acc[3][1] = MF(fa3, fb1, acc[3][1]);   \
    acc[3][2] = MF(fa3, fb2, acc[3][2]); acc[3][3] = MF(fa3, fb3, acc[3][3]);   \
    __builtin_amdgcn_s_setprio(0);                                              \
    BAR();                                                                      \
    v8bf fa4 = *(const v8bf*)&lds[sb + aRd + 2048];                             \
    v8bf fa5 = *(const v8bf*)&lds[sb + aRd + 2560];                             \
    v8bf fa6 = *(const v8bf*)&lds[sb + aRd + 3072];                             \
    v8bf fa7 = *(const v8bf*)&lds[sb + aRd + 3584];                             \
    if (STG) { GLDB((kt) + 3, 0); GLDB((kt) + 3, 1); }                          \
    if ((VM) == 8) asm volatile("s_waitcnt vmcnt(8)" ::: "memory");             \
    else if ((VM) == 4) asm volatile("s_waitcnt vmcnt(4)" ::: "memory");        \
    else if ((VM) == 0) asm volatile("s_waitcnt vmcnt(0)" ::: "memory");        \
    BAR();                                                                      \
    __builtin_amdgcn_s_setprio(1);                                              \
    acc[4][0] = MF(fa4, fb0, acc[4][0]); acc[4][1] = MF(fa4, fb1, acc[4][1]);   \
    acc[4][2] = MF(fa4, fb2, acc[4][2]); acc[4][3] = MF(fa4, fb3, acc[4][3]);   \
    acc[5][0] = MF(fa5, fb0, acc[5][0]); acc[5][1] = MF(fa5, fb1, acc[5][1]);   \
    acc[5][2] = MF(fa5, fb2, acc[5][2]); acc[5][3] = MF(fa5, fb3, acc[5][3]);   \
    acc[6][0] = MF(fa6, fb0, acc[6][0]); acc[6][1] = MF(fa6, fb1, acc[6][1]);   \
    acc[6][2] = MF(fa6, fb2, acc[6][2]); acc[6][3] = MF(fa6, fb3, acc[6][3]);   \
    acc[7][0] = MF(fa7, fb0, acc[7][0]); acc[7][1] = MF(fa7, fb1, acc[7][1]);   \
    acc[7][2] = MF(fa7, fb2, acc[7][2]); acc[7][3] = MF(fa7, fb3, acc[7][3]);   \
    __builtin_amdgcn_s_setprio(0);                                              \
    BAR();                                                                      \
  } while (0)

  for (int kt = 0; kt + 3 < NT; ++kt) KTILE(kt, 1, 8);
  KTILE(NT - 3, 0, 4);
  KTILE(NT - 2, 0, 0);
  KTILE(NT - 1, 0, -1);
#undef KTILE
#undef GLDA
#undef GLDB
#undef BAR

  // epilogue: C/D layout col=lane&15, row=(lane>>4)*4+rr
#pragma unroll
  for (int i = 0; i < 8; ++i) {
    const int rowb = m0 + wr * 128 + i * 16 + fq * 4;
#pragma unroll
    for (int j = 0; j < 4; ++j) {
      const int col = n0 + wc * 64 + j * 16 + frow;
      const float bv = bias[col];
#pragma unroll
      for (int rr = 0; rr < 4; ++rr) {
        float v = acc[i][j][rr] + bv;
        if (ACT) v = v * (1.f / (1.f + __expf(-1.702f * v)));  // QuickGELU
        const size_t off = (size_t)(rowb + rr) * N + col;
        if (RES) v += res[off];
        if (OUTF32) ((float*)out)[off] = v;
        else ((u16*)out)[off] = f2bf(v);
      }
    }
  }
}

// ---------------- attention: one block per (b,h); S=77 padded to 80 ----------------
__global__ __launch_bounds__(256) void attn_k(const u16* __restrict__ qkv, u16* __restrict__ ctx) {
  __shared__ u16 sQK[10240];        // sQ[80][64] @0, sK[80][64] @5120; later reused as sP[80][96]
  __shared__ u16 sVt[64 * 120];     // V transposed [d][k], stride 120
  __shared__ float sS[80][81];      // scores fp32
  const int tid = threadIdx.x;
  const int lane = tid & 63;
  const int wv = tid >> 6;
  const int b = blockIdx.x / 12;
  const int h = blockIdx.x % 12;
  u16* sQ = sQK;
  u16* sK = sQK + 5120;
  u16* sP = sQK;

  for (int i = tid; i < 10240 + 64 * 120; i += 256) {
    if (i < 10240) sQK[i] = 0; else sVt[i - 10240] = 0;
  }
  __syncthreads();

  const size_t tokBase = (size_t)(b * 77) * 2304 + h * 64;
  for (int c = tid; c < 77 * 8; c += 256) {
    const int row = c >> 3, k8 = (c & 7) * 8;
    const size_t src = tokBase + (size_t)row * 2304 + k8;
    *(u16x8*)&sQ[row * 64 + k8] = *(const u16x8*)&qkv[src];
    *(u16x8*)&sK[row * 64 + k8] = *(const u16x8*)&qkv[src + 768];
    u16x8 v = *(const u16x8*)&qkv[src + 1536];
#pragma unroll
    for (int j = 0; j < 8; ++j) sVt[(k8 + j) * 120 + row] = v[j];
  }
  __syncthreads();

  const int frow = lane & 15, fk = (lane >> 4) * 8;
  for (int t = wv; t < 25; t += 4) {
    const int it = t / 5, jt = t % 5;
    v4f acc = {0.f, 0.f, 0.f, 0.f};
#pragma unroll
    for (int kk = 0; kk < 2; ++kk) {
      v8bf a = *(const v8bf*)&sQ[(it * 16 + frow) * 64 + kk * 32 + fk];
      v8bf bb = *(const v8bf*)&sK[(jt * 16 + frow) * 64 + kk * 32 + fk];
      acc = MF(a, bb, acc);
    }
    const int col = jt * 16 + frow;
#pragma unroll
    for (int r = 0; r < 4; ++r) {
      const int row = it * 16 + (lane >> 4) * 4 + r;
      sS[row][col] = (col > row) ? -1e30f : acc[r];
    }
  }
  __syncthreads();

  if (tid < 80) {
    const int row = tid;
    float mx = -1e30f;
    for (int c2 = 0; c2 < 80; ++c2) mx = fmaxf(mx, sS[row][c2]);
    float sum = 0.f;
    for (int c2 = 0; c2 < 80; ++c2) { float e = __expf(sS[row][c2] - mx); sum += e; sS[row][c2] = e; }
    const float inv = 1.f / sum;
    for (int c2 = 0; c2 < 80; ++c2) sP[row * 96 + c2] = f2bf(sS[row][c2] * inv);
    for (int c2 = 80; c2 < 96; ++c2) sP[row * 96 + c2] = 0;
  }
  __syncthreads();

  const size_t outBase = (size_t)(b * 77) * 768 + h * 64;
  for (int t = wv; t < 20; t += 4) {
    const int it = t / 4, jt = t % 4;
    v4f acc = {0.f, 0.f, 0.f, 0.f};
#pragma unroll
    for (int kk = 0; kk < 3; ++kk) {
      v8bf a = *(const v8bf*)&sP[(it * 16 + frow) * 96 + kk * 32 + fk];
      v8bf bb = *(const v8bf*)&sVt[(jt * 16 + frow) * 120 + kk * 32 + fk];
      acc = MF(a, bb, acc);
    }
    const int col = jt * 16 + frow;
#pragma unroll
    for (int r = 0; r < 4; ++r) {
      const int row = it * 16 + (lane >> 4) * 4 + r;
      if (row < 77) ctx[outBase + (size_t)row * 768 + col] = f2bf(acc[r]);
    }
  }
}

// ---------------- launch ----------------
extern "C" void kernel_launch(void* const* d_in, const int* in_sizes, int n_in,
                              void* d_out, int out_size, void* d_ws, size_t ws_size,
                              hipStream_t stream) {
  const float* x    = (const float*)d_in[0];
  const float* ln1w = (const float*)d_in[1];
  const float* ln1b = (const float*)d_in[2];
  const float* qw   = (const float*)d_in[3];
  const float* qb   = (const float*)d_in[4];
  const float* kw   = (const float*)d_in[5];
  const float* kb   = (const float*)d_in[6];
  const float* vw   = (const float*)d_in[7];
  const float* vb   = (const float*)d_in[8];
  const float* ow   = (const float*)d_in[9];
  const float* ob   = (const float*)d_in[10];
  const float* ln2w = (const float*)d_in[11];
  const float* ln2b = (const float*)d_in[12];
  const float* f1wf = (const float*)d_in[13];
  const float* f1b  = (const float*)d_in[14];
  const float* f2wf = (const float*)d_in[15];
  const float* f2b  = (const float*)d_in[16];
  float* outp = (float*)d_out;

  char* p = (char*)d_ws;
  auto alloc = [&](size_t bytes) { char* r = p; p += (bytes + 255) & ~(size_t)255; return r; };
  u16* wqkv = (u16*)alloc((size_t)2304 * 768 * 2);   // rows: qw*0.125 | kw | vw
  u16* owb  = (u16*)alloc((size_t)768 * 768 * 2);
  u16* f1w  = (u16*)alloc((size_t)3072 * 768 * 2);
  u16* f2w  = (u16*)alloc((size_t)768 * 3072 * 2);
  float* qkvb = (float*)alloc(2304 * 4);
  u16* bufA = (u16*)alloc((size_t)M_TOK * 768 * 2);   // h -> ctx -> h2in
  u16* bufB = (u16*)alloc((size_t)M_TOK * 3072 * 2);  // qkv (2304 cols) -> h2 (3072 cols)

  cvt4_k<<<576, 256, 0, stream>>>(qw, wqkv, 147456, 0.125f);
  cvt4_k<<<576, 256, 0, stream>>>(kw, wqkv + 589824, 147456, 1.f);
  cvt4_k<<<576, 256, 0, stream>>>(vw, wqkv + 1179648, 147456, 1.f);
  cvt4_k<<<576, 256, 0, stream>>>(ow, owb, 147456, 1.f);
  cvt4_k<<<2304, 256, 0, stream>>>(f1wf, f1w, 589824, 1.f);
  cvt4_k<<<2304, 256, 0, stream>>>(f2wf, f2w, 589824, 1.f);
  qkvb_k<<<9, 256, 0, stream>>>(qb, kb, vb, qkvb);

  ln_k<<<M_TOK / 4, 256, 0, stream>>>(x, ln1w, ln1b, bufA, M_TOK);
  gemm256_k<0, 0, 0><<<154 * 9, 512, 0, stream>>>(bufA, wqkv, qkvb, nullptr, bufB, M_TOK, 2304, 768, 9);
  attn_k<<<512 * 12, 256, 0, stream>>>(bufB, bufA);
  gemm256_k<1, 0, 1><<<154 * 3, 512, 0, stream>>>(bufA, owb, ob, x, outp, M_TOK, 768, 768, 3);
  ln_k<<<M_TOK / 4, 256, 0, stream>>>(outp, ln2w, ln2b, bufA, M_TOK);
  gemm256_k<0, 1, 0><<<154 * 12, 512, 0, stream>>>(bufA, f1w, f1b, nullptr, bufB, M_TOK, 3072, 768, 12);
  gemm256_k<1, 0, 1><<<154 * 3, 512, 0, stream>>>(bufB, f2w, f2b, outp, outp, M_TOK, 768, 3072, 3);
}